// Round 6
// baseline (183.405 us; speedup 1.0000x reference)
//
#include <hip/hip_runtime.h>
#include <math.h>

// Problem constants (fixed by setup_inputs)
constexpr int BS = 16;
constexpr int NA = 8400;    // 80^2 + 40^2 + 20^2, strides 8/16/32
constexpr int NC = 80;
constexpr int MG = 128;
constexpr int TK = 13;
constexpr int NCAND = 1536; // max enumerated inside-candidates ~1251 (box<200^2)

// Output layout (floats), return order: labels, bboxes, scores, fg_mask, tgt_idx
constexpr int OFF_LBL = 0;
constexpr int OFF_BB  = OFF_LBL + BS * NA;
constexpr int OFF_SC  = OFF_BB  + BS * NA * 4;
constexpr int OFF_FG  = OFF_SC  + BS * NA * NC;
constexpr int OFF_TG  = OFF_FG  + BS * NA;

// CIoU with the arctan difference supplied by the caller (hot loops hoist the
// loop-invariant atanf). dat = atanf(w2/h2) - atanf(w1/h1).
__device__ __forceinline__ float ciou_pre(float gx, float gy, float gz, float gw,
                                          float px, float py, float pz, float pw,
                                          float dat) {
    const float eps = 1e-7f;
    float w1 = gz - gx, h1 = gw - gy + eps;
    float w2 = pz - px, h2 = pw - py + eps;
    float iw = fmaxf(fminf(gz, pz) - fmaxf(gx, px), 0.f);
    float ih = fmaxf(fminf(gw, pw) - fmaxf(gy, py), 0.f);
    float inter = iw * ih;
    float uni = w1 * h1 + w2 * h2 - inter + eps;
    float iou = inter / uni;
    float cw = fmaxf(gz, pz) - fminf(gx, px);
    float ch = fmaxf(gw, pw) - fminf(gy, py);
    float c2 = cw * cw + ch * ch + eps;
    float dx = px + pz - gx - gz;
    float dy = py + pw - gy - gw;
    float rho2 = (dx * dx + dy * dy) * 0.25f;
    float v = 0.4052847345693511f * dat * dat;   // 4/pi^2
    float alpha = v / (v - iou + (1.f + eps));
    return iou - (rho2 / c2 + v * alpha);
}

__device__ __forceinline__ bool inside_gt(float ax, float ay,
                                          float gx, float gy, float gz, float gw) {
    float d = fminf(fminf(ax - gx, ay - gy), fminf(gz - ax, gw - ay));
    return d > 1e-9f;
}

// anchor index -> grid-point coords, bitwise == anc[] ((i+0.5)*s, s pow2)
__device__ __forceinline__ void anchor_xy(int a, float& ax, float& ay) {
    if (a < 6400)      { int iy = a / 80;        int ix = a - iy * 80;           ax = (ix + 0.5f) * 8.f;  ay = (iy + 0.5f) * 8.f; }
    else if (a < 8000) { int r = a - 6400; int iy = r / 40; int ix = r - iy * 40; ax = (ix + 0.5f) * 16.f; ay = (iy + 0.5f) * 16.f; }
    else               { int r = a - 8000; int iy = r / 20; int ix = r - iy * 20; ax = (ix + 0.5f) * 32.f; ay = (iy + 0.5f) * 32.f; }
}

// K1: one 2-wave block per (b,m). Enumerate candidate anchors from the box's
// grid rectangles (3 levels), compact positives to LDS, 13 argmax rounds
// (exact lax.top_k semantics: lowest-index ties + npos<13 zero-fill).
// Also publishes the row's gt-side atanf into at_g_tbl for k_assign.
__global__ __launch_bounds__(128) void k_topk(
    const float* __restrict__ pd_scores, const float* __restrict__ pd_bboxes,
    const int* __restrict__ gt_labels, const float* __restrict__ gt_bboxes,
    const float* __restrict__ mask_gt,
    int* __restrict__ fg_cnt, int* __restrict__ fg_m,
    float* __restrict__ at_g_tbl)
{
    __shared__ float cv[NCAND];
    __shared__ int   ca[NCAND];
    __shared__ int   s_cnt;
    __shared__ unsigned s_pm;           // "align>0" mask for anchors 0..31
    __shared__ float s_wv[2];
    __shared__ int   s_wk[2];

    int bm = blockIdx.x;
    if (mask_gt[bm] <= 0.f) return;
    int b = bm >> 7;                    // MG = 128
    int m = bm & (MG - 1);
    int tid = threadIdx.x;

    if (tid == 0) { s_cnt = 0; s_pm = 0u; }
    __syncthreads();

    const float4 g = *reinterpret_cast<const float4*>(gt_bboxes + bm * 4);
    const int lbl = gt_labels[bm];
    const float* pbb = pd_bboxes + (size_t)b * NA * 4;
    const float* psc = pd_scores + (size_t)b * NA * NC;
    const float at_g = atanf((g.z - g.x) / (g.w - g.y + 1e-7f));  // block-invariant
    if (tid == 0) at_g_tbl[bm] = at_g;

    auto do_level = [&](float s, int n, int base) {
        // conservative rectangle (+-1 cell); exact inside_gt per candidate
        // keeps the positive set bitwise-identical.
        int xlo = max(0, (int)floorf(g.x / s - 0.5f) - 1);
        int xhi = min(n - 1, (int)ceilf(g.z / s - 0.5f) + 1);
        int ylo = max(0, (int)floorf(g.y / s - 0.5f) - 1);
        int yhi = min(n - 1, (int)ceilf(g.w / s - 0.5f) + 1);
        int w = xhi - xlo + 1, h = yhi - ylo + 1;
        if (w <= 0 || h <= 0) return;
        int cnt = w * h;
        for (int idx = tid; idx < cnt; idx += 128) {
            int iy = ylo + idx / w;
            int ix = xlo + idx - (idx / w) * w;
            float ax = (ix + 0.5f) * s;
            float ay = (iy + 0.5f) * s;
            if (!inside_gt(ax, ay, g.x, g.y, g.z, g.w)) continue;
            int a = base + iy * n + ix;
            float4 p = *reinterpret_cast<const float4*>(pbb + (size_t)a * 4);
            float dat = atanf((p.z - p.x) / (p.w - p.y + 1e-7f)) - at_g;
            float ov = fmaxf(ciou_pre(g.x, g.y, g.z, g.w, p.x, p.y, p.z, p.w, dat), 0.f);
            float sc = psc[(size_t)a * NC + lbl];
            float ov2 = ov * ov;
            float al = sc * ov2 * ov2 * ov2;     // score^1 * ov^6
            if (al > 0.f) {
                int slot = atomicAdd(&s_cnt, 1);
                if (slot < NCAND) { cv[slot] = al; ca[slot] = a; }
                if (a < 32) atomicOr(&s_pm, 1u << a);
            }
        }
    };
    do_level(8.f, 80, 0);
    do_level(16.f, 40, 6400);
    do_level(32.f, 20, 8000);
    __syncthreads();

    int npos = min(s_cnt, NCAND);
    int rounds = min(npos, TK);
    int* fgc = fg_cnt + b * NA;
    int* fgm = fg_m + b * NA;

    for (int k = 0; k < rounds; ++k) {
        float bv = -1.f; int bk = 0x7fffffff;
        for (int p = tid; p < npos; p += 128) {
            float v = cv[p];
            int key = (ca[p] << 11) | p;         // anchor high bits: ties -> lowest anchor
            if (v > bv || (v == bv && key < bk)) { bv = v; bk = key; }
        }
        #pragma unroll
        for (int off = 32; off > 0; off >>= 1) {
            float v2 = __shfl_down(bv, off);
            int   k2 = __shfl_down(bk, off);
            if (v2 > bv || (v2 == bv && k2 < bk)) { bv = v2; bk = k2; }
        }
        int wid = tid >> 6;
        if ((tid & 63) == 0) { s_wv[wid] = bv; s_wk[wid] = bk; }
        __syncthreads();
        if (tid == 0) {
            if (s_wv[1] > bv || (s_wv[1] == bv && s_wk[1] < bk)) { bv = s_wv[1]; bk = s_wk[1]; }
            int slot = bk & 2047;
            int a = bk >> 11;
            cv[slot] = -1.f;                     // remove winner
            atomicAdd(&fgc[a], 1);
            fgm[a] = m;                          // unique writer when final cnt==1
        }
        __syncthreads();
    }

    // npos < TK: top_k pads with globally lowest-index zero-valued anchors
    // (indices provably < 26 < 32); mask_in_gts then filters them.
    if (tid == 0) {
        int need = TK - rounds;
        unsigned pm = s_pm;
        for (int idx = 0; idx < 32 && need > 0; ++idx) {
            if (!((pm >> idx) & 1u)) {
                float ax = (idx + 0.5f) * 8.f, ay = 4.f;
                if (inside_gt(ax, ay, g.x, g.y, g.z, g.w)) {
                    atomicAdd(&fgc[idx], 1);
                    fgm[idx] = m;
                }
                --need;
            }
        }
    }
}

// K2: per anchor, fully fused. cnt==1 direct; cnt>1 resolved inline via
// 128-iteration argmax over masked overlaps (first-max tie-break, gt-side
// atanf from table). Writes labels/bboxes/fg/tgt + per-row pos maxes.
__global__ __launch_bounds__(256) void k_assign(
    const float* __restrict__ pd_scores, const float* __restrict__ pd_bboxes,
    const int* __restrict__ gt_labels, const float* __restrict__ gt_bboxes,
    const float* __restrict__ mask_gt, const float* __restrict__ at_g_tbl,
    const int* __restrict__ fg_cnt, const int* __restrict__ fg_m,
    float* __restrict__ out, float* __restrict__ am_ws,
    int* __restrict__ gi_ws, int* __restrict__ lbl_ws,
    unsigned* __restrict__ pos_am, unsigned* __restrict__ pos_ov)
{
    int i = blockIdx.x * 256 + threadIdx.x;      // grid exact: 134400 = 525*256
    int cnt = fg_cnt[i];
    int b = i / NA, a = i - b * NA;
    int gbase = b * MG;

    int t = 0;
    float bov = -1.f;
    bool multi = cnt > 1;
    if (multi) {
        float ax, ay; anchor_xy(a, ax, ay);
        float4 p = *reinterpret_cast<const float4*>(pd_bboxes + (size_t)i * 4);
        float at_p = atanf((p.z - p.x) / (p.w - p.y + 1e-7f));  // anchor-invariant
        for (int mm = 0; mm < MG; ++mm) {
            int gi = gbase + mm;
            float ov = 0.f;
            if (mask_gt[gi] > 0.f) {
                float4 gg = *reinterpret_cast<const float4*>(gt_bboxes + gi * 4);
                if (inside_gt(ax, ay, gg.x, gg.y, gg.z, gg.w)) {
                    float dat = at_p - at_g_tbl[gi];
                    ov = fmaxf(ciou_pre(gg.x, gg.y, gg.z, gg.w, p.x, p.y, p.z, p.w, dat), 0.f);
                }
            }
            if (ov > bov) { bov = ov; t = mm; }  // first max
        }
    } else if (cnt == 1) {
        t = fg_m[i];
    }

    int gi = gbase + t;
    float4 g = *reinterpret_cast<const float4*>(gt_bboxes + gi * 4);
    int lraw = gt_labels[gi];
    int lbl = max(lraw, 0);

    float am = 0.f, ovv = 0.f;
    if (multi) {
        if (bov > 0.f) {                         // bov>0 implies mask && inside at t
            float sc = pd_scores[(size_t)i * NC + lraw];
            float o2 = bov * bov;
            am = sc * o2 * o2 * o2;
            ovv = bov;
        }
    } else if (cnt == 1) {
        if (mask_gt[gi] > 0.f) {
            float ax, ay; anchor_xy(a, ax, ay);
            if (inside_gt(ax, ay, g.x, g.y, g.z, g.w)) {
                float4 p = *reinterpret_cast<const float4*>(pd_bboxes + (size_t)i * 4);
                float dat = atanf((p.z - p.x) / (p.w - p.y + 1e-7f)) - at_g_tbl[gi];
                float ov = fmaxf(ciou_pre(g.x, g.y, g.z, g.w, p.x, p.y, p.z, p.w, dat), 0.f);
                float sc = pd_scores[(size_t)i * NC + lraw];
                float ov2 = ov * ov;
                am = sc * ov2 * ov2 * ov2;
                ovv = ov;
            }
        }
    }

    if (cnt > 0) {
        atomicMax(&pos_am[gi], __float_as_uint(am));
        atomicMax(&pos_ov[gi], __float_as_uint(ovv));
        am_ws[i] = am; gi_ws[i] = gi; lbl_ws[i] = lbl;
    } else {
        gi_ws[i] = -1;                           // background
    }

    out[OFF_LBL + i] = (float)lbl;
    reinterpret_cast<float4*>(out + OFF_BB)[i] = g;
    out[OFF_FG + i] = cnt ? 1.f : 0.f;
    out[OFF_TG + i] = (float)t;
}

// K3: dense coalesced write of target_scores (replaces memset + scatter).
__global__ __launch_bounds__(256) void k_scores(
    const float* __restrict__ am_ws, const int* __restrict__ gi_ws,
    const int* __restrict__ lbl_ws,
    const unsigned* __restrict__ pos_am, const unsigned* __restrict__ pos_ov,
    float* __restrict__ out_scores)
{
    constexpr int NQ = NC / 4;                   // 20 float4s per anchor
    int idx = blockIdx.x * 256 + threadIdx.x;    // grid exact: 134400*20 = 10500*256
    int i = idx / NQ;
    int q = idx - i * NQ;
    float4 v = {0.f, 0.f, 0.f, 0.f};
    int gi = gi_ws[i];
    if (gi >= 0) {
        int lbl = lbl_ws[i];
        if ((lbl >> 2) == q) {
            float norm = am_ws[i] * __uint_as_float(pos_ov[gi]) /
                         (__uint_as_float(pos_am[gi]) + 1e-9f);
            reinterpret_cast<float*>(&v)[lbl & 3] = norm;
        }
    }
    reinterpret_cast<float4*>(out_scores)[idx] = v;
}

extern "C" void kernel_launch(void* const* d_in, const int* in_sizes, int n_in,
                              void* d_out, int out_size, void* d_ws, size_t ws_size,
                              hipStream_t stream) {
    const float* pd_scores = (const float*)d_in[0];
    const float* pd_bboxes = (const float*)d_in[1];
    const int*   gt_labels = (const int*)d_in[3];
    const float* gt_bboxes = (const float*)d_in[4];
    const float* mask_gt   = (const float*)d_in[5];
    float* out = (float*)d_out;

    // Workspace carve. Zeroed region first.
    unsigned char* w = (unsigned char*)d_ws;
    size_t off = 0;
    int*      fg_cnt   = (int*)(w + off);      off += (size_t)BS * NA * 4;
    unsigned* pos_am   = (unsigned*)(w + off); off += (size_t)BS * MG * 4;
    unsigned* pos_ov   = (unsigned*)(w + off); off += (size_t)BS * MG * 4;
    size_t zero_bytes = off;
    int*      fg_m     = (int*)(w + off);      off += (size_t)BS * NA * 4;
    float*    am_ws    = (float*)(w + off);    off += (size_t)BS * NA * 4;
    int*      gi_ws    = (int*)(w + off);      off += (size_t)BS * NA * 4;
    int*      lbl_ws   = (int*)(w + off);      off += (size_t)BS * NA * 4;
    float*    at_g_tbl = (float*)(w + off);    off += (size_t)BS * MG * 4;

    hipMemsetAsync(w, 0, zero_bytes, stream);

    k_topk<<<BS * MG, 128, 0, stream>>>(pd_scores, pd_bboxes, gt_labels,
                                        gt_bboxes, mask_gt, fg_cnt, fg_m,
                                        at_g_tbl);

    int nA = BS * NA;                            // 134400 = 525 * 256
    k_assign<<<nA / 256, 256, 0, stream>>>(
        pd_scores, pd_bboxes, gt_labels, gt_bboxes, mask_gt, at_g_tbl,
        fg_cnt, fg_m, out, am_ws, gi_ws, lbl_ws, pos_am, pos_ov);

    k_scores<<<nA * (NC / 4) / 256, 256, 0, stream>>>(
        am_ws, gi_ws, lbl_ws, pos_am, pos_ov, out + OFF_SC);
}

// Round 7
// 166.176 us; speedup vs baseline: 1.1037x; 1.1037x over previous
//
#include <hip/hip_runtime.h>
#include <math.h>

// Problem constants (fixed by setup_inputs)
constexpr int BS = 16;
constexpr int NA = 8400;    // 80^2 + 40^2 + 20^2, strides 8/16/32
constexpr int NC = 80;
constexpr int MG = 128;
constexpr int TK = 13;
constexpr int NCAND = 1536; // max enumerated inside-candidates ~1251 (box<200^2)
constexpr int QCAP = 65536; // multi queue (observed ~23K)

// Output layout (floats), return order: labels, bboxes, scores, fg_mask, tgt_idx
constexpr int OFF_LBL = 0;
constexpr int OFF_BB  = OFF_LBL + BS * NA;
constexpr int OFF_SC  = OFF_BB  + BS * NA * 4;
constexpr int OFF_FG  = OFF_SC  + BS * NA * NC;
constexpr int OFF_TG  = OFF_FG  + BS * NA;

// CIoU with the arctan difference supplied by the caller (hot loops hoist the
// loop-invariant atanf). dat = atanf(w2/h2) - atanf(w1/h1).
__device__ __forceinline__ float ciou_pre(float gx, float gy, float gz, float gw,
                                          float px, float py, float pz, float pw,
                                          float dat) {
    const float eps = 1e-7f;
    float w1 = gz - gx, h1 = gw - gy + eps;
    float w2 = pz - px, h2 = pw - py + eps;
    float iw = fmaxf(fminf(gz, pz) - fmaxf(gx, px), 0.f);
    float ih = fmaxf(fminf(gw, pw) - fmaxf(gy, py), 0.f);
    float inter = iw * ih;
    float uni = w1 * h1 + w2 * h2 - inter + eps;
    float iou = inter / uni;
    float cw = fmaxf(gz, pz) - fminf(gx, px);
    float ch = fmaxf(gw, pw) - fminf(gy, py);
    float c2 = cw * cw + ch * ch + eps;
    float dx = px + pz - gx - gz;
    float dy = py + pw - gy - gw;
    float rho2 = (dx * dx + dy * dy) * 0.25f;
    float v = 0.4052847345693511f * dat * dat;   // 4/pi^2
    float alpha = v / (v - iou + (1.f + eps));
    return iou - (rho2 / c2 + v * alpha);
}

__device__ __forceinline__ bool inside_gt(float ax, float ay,
                                          float gx, float gy, float gz, float gw) {
    float d = fminf(fminf(ax - gx, ay - gy), fminf(gz - ax, gw - ay));
    return d > 1e-9f;
}

// anchor index -> grid-point coords, bitwise == anc[] ((i+0.5)*s, s pow2)
__device__ __forceinline__ void anchor_xy(int a, float& ax, float& ay) {
    if (a < 6400)      { int iy = a / 80;        int ix = a - iy * 80;           ax = (ix + 0.5f) * 8.f;  ay = (iy + 0.5f) * 8.f; }
    else if (a < 8000) { int r = a - 6400; int iy = r / 40; int ix = r - iy * 40; ax = (ix + 0.5f) * 16.f; ay = (iy + 0.5f) * 16.f; }
    else               { int r = a - 8000; int iy = r / 20; int ix = r - iy * 20; ax = (ix + 0.5f) * 32.f; ay = (iy + 0.5f) * 32.f; }
}

// K1: one WAVE per (b,m). Enumerate candidate anchors from the box's grid
// rectangles (3 levels), compact positives to LDS, 13 shuffle-argmax rounds
// (exact lax.top_k semantics: lowest-index ties + npos<13 zero-fill).
// Publishes the row's gt-side atanf into at_g_tbl for k_assign/k_fix.
__global__ __launch_bounds__(64) void k_topk(
    const float* __restrict__ pd_scores, const float* __restrict__ pd_bboxes,
    const int* __restrict__ gt_labels, const float* __restrict__ gt_bboxes,
    const float* __restrict__ mask_gt,
    int* __restrict__ fg_cnt, int* __restrict__ fg_m,
    float* __restrict__ at_g_tbl)
{
    __shared__ float cv[NCAND];
    __shared__ int   ca[NCAND];
    __shared__ int   s_cnt;
    __shared__ unsigned s_pm;           // "align>0" mask for anchors 0..31

    int bm = blockIdx.x;
    if (mask_gt[bm] <= 0.f) return;
    int b = bm >> 7;                    // MG = 128
    int m = bm & (MG - 1);
    int tid = threadIdx.x;

    if (tid == 0) { s_cnt = 0; s_pm = 0u; }
    __syncthreads();

    const float4 g = *reinterpret_cast<const float4*>(gt_bboxes + bm * 4);
    const int lbl = gt_labels[bm];
    const float* pbb = pd_bboxes + (size_t)b * NA * 4;
    const float* psc = pd_scores + (size_t)b * NA * NC;
    const float at_g = atanf((g.z - g.x) / (g.w - g.y + 1e-7f));  // block-invariant
    if (tid == 0) at_g_tbl[bm] = at_g;

    auto do_level = [&](float s, int n, int base) {
        // conservative rectangle (+-1 cell); exact inside_gt per candidate
        // keeps the positive set bitwise-identical.
        int xlo = max(0, (int)floorf(g.x / s - 0.5f) - 1);
        int xhi = min(n - 1, (int)ceilf(g.z / s - 0.5f) + 1);
        int ylo = max(0, (int)floorf(g.y / s - 0.5f) - 1);
        int yhi = min(n - 1, (int)ceilf(g.w / s - 0.5f) + 1);
        int w = xhi - xlo + 1, h = yhi - ylo + 1;
        if (w <= 0 || h <= 0) return;
        int cnt = w * h;
        for (int idx = tid; idx < cnt; idx += 64) {
            int iy = ylo + idx / w;
            int ix = xlo + idx - (idx / w) * w;
            float ax = (ix + 0.5f) * s;
            float ay = (iy + 0.5f) * s;
            if (!inside_gt(ax, ay, g.x, g.y, g.z, g.w)) continue;
            int a = base + iy * n + ix;
            float4 p = *reinterpret_cast<const float4*>(pbb + (size_t)a * 4);
            float dat = atanf((p.z - p.x) / (p.w - p.y + 1e-7f)) - at_g;
            float ov = fmaxf(ciou_pre(g.x, g.y, g.z, g.w, p.x, p.y, p.z, p.w, dat), 0.f);
            float sc = psc[(size_t)a * NC + lbl];
            float ov2 = ov * ov;
            float al = sc * ov2 * ov2 * ov2;     // score^1 * ov^6
            if (al > 0.f) {
                int slot = atomicAdd(&s_cnt, 1);
                if (slot < NCAND) { cv[slot] = al; ca[slot] = a; }
                if (a < 32) atomicOr(&s_pm, 1u << a);
            }
        }
    };
    do_level(8.f, 80, 0);
    do_level(16.f, 40, 6400);
    do_level(32.f, 20, 8000);
    __syncthreads();

    int npos = min(s_cnt, NCAND);
    int rounds = min(npos, TK);
    int* fgc = fg_cnt + b * NA;
    int* fgm = fg_m + b * NA;

    for (int k = 0; k < rounds; ++k) {
        float bv = -1.f; int bk = 0x7fffffff;
        for (int p = tid; p < npos; p += 64) {
            float v = cv[p];
            int key = (ca[p] << 11) | p;         // anchor high bits: ties -> lowest anchor
            if (v > bv || (v == bv && key < bk)) { bv = v; bk = key; }
        }
        #pragma unroll
        for (int off = 32; off > 0; off >>= 1) {
            float v2 = __shfl_down(bv, off);
            int   k2 = __shfl_down(bk, off);
            if (v2 > bv || (v2 == bv && k2 < bk)) { bv = v2; bk = k2; }
        }
        if (tid == 0) {
            int slot = bk & 2047;
            int a = bk >> 11;
            cv[slot] = -1.f;                     // remove winner
            atomicAdd(&fgc[a], 1);
            fgm[a] = m;                          // unique writer when final cnt==1
        }
        __syncthreads();
    }

    // npos < TK: top_k pads with globally lowest-index zero-valued anchors
    // (indices provably < 26 < 32); mask_in_gts then filters them.
    if (tid == 0) {
        int need = TK - rounds;
        unsigned pm = s_pm;
        for (int idx = 0; idx < 32 && need > 0; ++idx) {
            if (!((pm >> idx) & 1u)) {
                float ax = (idx + 0.5f) * 8.f, ay = 4.f;
                if (inside_gt(ax, ay, g.x, g.y, g.z, g.w)) {
                    atomicAdd(&fgc[idx], 1);
                    fgm[idx] = m;
                }
                --need;
            }
        }
    }
}

// K2: per anchor. cnt<=1 resolved inline; cnt>1 appended to multi_q via
// wave-ballot compaction + one global atomicAdd per block (no hot-address
// atomic streams). 134400 = 525*256, so every block is full.
__global__ __launch_bounds__(256) void k_assign(
    const float* __restrict__ pd_scores, const float* __restrict__ pd_bboxes,
    const int* __restrict__ gt_labels, const float* __restrict__ gt_bboxes,
    const float* __restrict__ mask_gt, const float* __restrict__ at_g_tbl,
    const int* __restrict__ fg_cnt, const int* __restrict__ fg_m,
    float* __restrict__ out, float* __restrict__ am_ws,
    int* __restrict__ gi_ws, int* __restrict__ lbl_ws,
    unsigned* __restrict__ pos_am, unsigned* __restrict__ pos_ov,
    int* __restrict__ multi_cnt, int* __restrict__ multi_q)
{
    __shared__ int s_cnt, s_base;
    int tid = threadIdx.x;
    if (tid == 0) s_cnt = 0;
    __syncthreads();

    int i = blockIdx.x * 256 + tid;
    int cnt = fg_cnt[i];
    bool multi = cnt > 1;

    // wave-level compaction of multi-anchors
    unsigned long long mk = __ballot(multi);
    int lane = tid & 63;
    int rank = __popcll(mk & ((1ull << lane) - 1ull));
    int wsum = __popcll(mk);
    int wbase = 0;
    if (lane == 0 && wsum) wbase = atomicAdd(&s_cnt, wsum);
    wbase = __shfl(wbase, 0);
    __syncthreads();
    if (tid == 0 && s_cnt) s_base = atomicAdd(multi_cnt, s_cnt);
    __syncthreads();

    if (multi) {
        multi_q[s_base + wbase + rank] = i;      // outputs written by k_fix
        return;
    }

    int b = i / NA, a = i - b * NA;
    int t = (cnt == 1) ? fg_m[i] : 0;
    int gi = b * MG + t;
    float4 g = *reinterpret_cast<const float4*>(gt_bboxes + gi * 4);
    int lraw = gt_labels[gi];
    int lbl = max(lraw, 0);

    if (cnt == 1) {
        float am = 0.f, ovv = 0.f;
        if (mask_gt[gi] > 0.f) {
            float ax, ay; anchor_xy(a, ax, ay);
            if (inside_gt(ax, ay, g.x, g.y, g.z, g.w)) {
                float4 p = *reinterpret_cast<const float4*>(pd_bboxes + (size_t)i * 4);
                float dat = atanf((p.z - p.x) / (p.w - p.y + 1e-7f)) - at_g_tbl[gi];
                float ov = fmaxf(ciou_pre(g.x, g.y, g.z, g.w, p.x, p.y, p.z, p.w, dat), 0.f);
                float sc = pd_scores[(size_t)i * NC + lraw];
                float ov2 = ov * ov;
                am = sc * ov2 * ov2 * ov2;
                ovv = ov;
            }
        }
        atomicMax(&pos_am[gi], __float_as_uint(am));
        atomicMax(&pos_ov[gi], __float_as_uint(ovv));
        am_ws[i] = am; gi_ws[i] = gi; lbl_ws[i] = lbl;
    } else {
        gi_ws[i] = -1;                           // background: no score write
    }

    out[OFF_LBL + i] = (float)lbl;
    reinterpret_cast<float4*>(out + OFF_BB)[i] = g;
    out[OFF_FG + i] = cnt ? 1.f : 0.f;
    out[OFF_TG + i] = (float)t;
}

// K3: one wave per multi-assigned anchor — argmax over 128 masked overlaps
// (2 per lane + shuffle reduce, first-max tie-break), gt atanf from table.
__global__ __launch_bounds__(256) void k_fix(
    const float* __restrict__ pd_scores, const float* __restrict__ pd_bboxes,
    const int* __restrict__ gt_labels, const float* __restrict__ gt_bboxes,
    const float* __restrict__ mask_gt, const float* __restrict__ at_g_tbl,
    const int* __restrict__ multi_cnt, const int* __restrict__ multi_q,
    float* __restrict__ out, float* __restrict__ am_ws,
    int* __restrict__ gi_ws, int* __restrict__ lbl_ws,
    unsigned* __restrict__ pos_am, unsigned* __restrict__ pos_ov)
{
    int gtid = blockIdx.x * 256 + threadIdx.x;
    int wave = gtid >> 6;
    int lane = gtid & 63;
    int nwaves = (gridDim.x * 256) >> 6;
    int qn = *multi_cnt;

    for (int qi = wave; qi < qn; qi += nwaves) {
        int i = multi_q[qi];
        int b = i / NA, a = i - b * NA;
        float ax, ay; anchor_xy(a, ax, ay);
        float4 p = *reinterpret_cast<const float4*>(pd_bboxes + (size_t)i * 4);
        float at_p = atanf((p.z - p.x) / (p.w - p.y + 1e-7f));  // anchor-invariant

        auto ovm = [&](int mm) -> float {
            int gi = b * MG + mm;
            float ov = 0.f;
            if (mask_gt[gi] > 0.f) {
                float4 gg = *reinterpret_cast<const float4*>(gt_bboxes + gi * 4);
                if (inside_gt(ax, ay, gg.x, gg.y, gg.z, gg.w)) {
                    float dat = at_p - at_g_tbl[gi];
                    ov = fmaxf(ciou_pre(gg.x, gg.y, gg.z, gg.w, p.x, p.y, p.z, p.w, dat), 0.f);
                }
            }
            return ov;
        };
        float ov0 = ovm(lane);
        float ov1 = ovm(lane + 64);
        float bov; int bm_;
        if (ov1 > ov0) { bov = ov1; bm_ = lane + 64; }
        else           { bov = ov0; bm_ = lane; }
        #pragma unroll
        for (int off = 32; off > 0; off >>= 1) {
            float v2 = __shfl_down(bov, off);
            int   m2 = __shfl_down(bm_, off);
            if (v2 > bov || (v2 == bov && m2 < bm_)) { bov = v2; bm_ = m2; }
        }
        if (lane == 0) {
            int t = bm_;
            int gi = b * MG + t;
            int lraw = gt_labels[gi];
            int lbl = max(lraw, 0);
            float am = 0.f;
            if (bov > 0.f) {                     // bov>0 implies mask&&inside at t
                float sc = pd_scores[(size_t)i * NC + lraw];
                float o2 = bov * bov;
                am = sc * o2 * o2 * o2;
            }
            atomicMax(&pos_am[gi], __float_as_uint(am));
            atomicMax(&pos_ov[gi], __float_as_uint(bov));
            float4 g = *reinterpret_cast<const float4*>(gt_bboxes + gi * 4);
            out[OFF_LBL + i] = (float)lbl;
            reinterpret_cast<float4*>(out + OFF_BB)[i] = g;
            out[OFF_FG + i] = 1.f;
            out[OFF_TG + i] = (float)t;
            am_ws[i] = am; gi_ws[i] = gi; lbl_ws[i] = lbl;
        }
    }
}

// K4: dense coalesced write of target_scores (no memset, no scatter atomics).
__global__ __launch_bounds__(256) void k_scores(
    const float* __restrict__ am_ws, const int* __restrict__ gi_ws,
    const int* __restrict__ lbl_ws,
    const unsigned* __restrict__ pos_am, const unsigned* __restrict__ pos_ov,
    float* __restrict__ out_scores)
{
    constexpr int NQ = NC / 4;                   // 20 float4s per anchor
    int idx = blockIdx.x * 256 + threadIdx.x;    // grid exact: 134400*20 = 10500*256
    int i = idx / NQ;
    int q = idx - i * NQ;
    float4 v = {0.f, 0.f, 0.f, 0.f};
    int gi = gi_ws[i];
    if (gi >= 0) {
        int lbl = lbl_ws[i];
        if ((lbl >> 2) == q) {
            float norm = am_ws[i] * __uint_as_float(pos_ov[gi]) /
                         (__uint_as_float(pos_am[gi]) + 1e-9f);
            reinterpret_cast<float*>(&v)[lbl & 3] = norm;
        }
    }
    reinterpret_cast<float4*>(out_scores)[idx] = v;
}

extern "C" void kernel_launch(void* const* d_in, const int* in_sizes, int n_in,
                              void* d_out, int out_size, void* d_ws, size_t ws_size,
                              hipStream_t stream) {
    const float* pd_scores = (const float*)d_in[0];
    const float* pd_bboxes = (const float*)d_in[1];
    const int*   gt_labels = (const int*)d_in[3];
    const float* gt_bboxes = (const float*)d_in[4];
    const float* mask_gt   = (const float*)d_in[5];
    float* out = (float*)d_out;

    // Workspace carve. Zeroed region first.
    unsigned char* w = (unsigned char*)d_ws;
    size_t off = 0;
    int*      fg_cnt    = (int*)(w + off);      off += (size_t)BS * NA * 4;
    unsigned* pos_am    = (unsigned*)(w + off); off += (size_t)BS * MG * 4;
    unsigned* pos_ov    = (unsigned*)(w + off); off += (size_t)BS * MG * 4;
    int*      multi_cnt = (int*)(w + off);      off += 4;
    size_t zero_bytes = off;
    int*      fg_m      = (int*)(w + off);      off += (size_t)BS * NA * 4;
    float*    am_ws     = (float*)(w + off);    off += (size_t)BS * NA * 4;
    int*      gi_ws     = (int*)(w + off);      off += (size_t)BS * NA * 4;
    int*      lbl_ws    = (int*)(w + off);      off += (size_t)BS * NA * 4;
    float*    at_g_tbl  = (float*)(w + off);    off += (size_t)BS * MG * 4;
    int*      multi_q   = (int*)(w + off);      off += (size_t)QCAP * 4;

    hipMemsetAsync(w, 0, zero_bytes, stream);

    k_topk<<<BS * MG, 64, 0, stream>>>(pd_scores, pd_bboxes, gt_labels,
                                       gt_bboxes, mask_gt, fg_cnt, fg_m,
                                       at_g_tbl);

    int nA = BS * NA;                            // 134400 = 525 * 256
    k_assign<<<nA / 256, 256, 0, stream>>>(
        pd_scores, pd_bboxes, gt_labels, gt_bboxes, mask_gt, at_g_tbl,
        fg_cnt, fg_m, out, am_ws, gi_ws, lbl_ws, pos_am, pos_ov,
        multi_cnt, multi_q);

    // ~23K multi anchors, one wave each: 2048 blocks x 4 waves = 8192 waves.
    k_fix<<<2048, 256, 0, stream>>>(
        pd_scores, pd_bboxes, gt_labels, gt_bboxes, mask_gt, at_g_tbl,
        multi_cnt, multi_q, out, am_ws, gi_ws, lbl_ws, pos_am, pos_ov);

    k_scores<<<nA * (NC / 4) / 256, 256, 0, stream>>>(
        am_ws, gi_ws, lbl_ws, pos_am, pos_ov, out + OFF_SC);
}

// Round 8
// 163.467 us; speedup vs baseline: 1.1220x; 1.0166x over previous
//
#include <hip/hip_runtime.h>
#include <math.h>

// Problem constants (fixed by setup_inputs)
constexpr int BS = 16;
constexpr int NA = 8400;    // 80^2 + 40^2 + 20^2, strides 8/16/32
constexpr int NC = 80;
constexpr int MG = 128;
constexpr int TK = 13;
constexpr int NCAND = 1536; // max enumerated inside-candidates ~1140 (box<200^2)

// Output layout (floats), return order: labels, bboxes, scores, fg_mask, tgt_idx
constexpr int OFF_LBL = 0;
constexpr int OFF_BB  = OFF_LBL + BS * NA;
constexpr int OFF_SC  = OFF_BB  + BS * NA * 4;
constexpr int OFF_FG  = OFF_SC  + BS * NA * NC;
constexpr int OFF_TG  = OFF_FG  + BS * NA;

// CIoU with the arctan difference supplied by the caller (hot loops hoist the
// loop-invariant atanf). dat = atanf(w2/h2) - atanf(w1/h1).
__device__ __forceinline__ float ciou_pre(float gx, float gy, float gz, float gw,
                                          float px, float py, float pz, float pw,
                                          float dat) {
    const float eps = 1e-7f;
    float w1 = gz - gx, h1 = gw - gy + eps;
    float w2 = pz - px, h2 = pw - py + eps;
    float iw = fmaxf(fminf(gz, pz) - fmaxf(gx, px), 0.f);
    float ih = fmaxf(fminf(gw, pw) - fmaxf(gy, py), 0.f);
    float inter = iw * ih;
    float uni = w1 * h1 + w2 * h2 - inter + eps;
    float iou = inter / uni;
    float cw = fmaxf(gz, pz) - fminf(gx, px);
    float ch = fmaxf(gw, pw) - fminf(gy, py);
    float c2 = cw * cw + ch * ch + eps;
    float dx = px + pz - gx - gz;
    float dy = py + pw - gy - gw;
    float rho2 = (dx * dx + dy * dy) * 0.25f;
    float v = 0.4052847345693511f * dat * dat;   // 4/pi^2
    float alpha = v / (v - iou + (1.f + eps));
    return iou - (rho2 / c2 + v * alpha);
}

__device__ __forceinline__ bool inside_gt(float ax, float ay,
                                          float gx, float gy, float gz, float gw) {
    float d = fminf(fminf(ax - gx, ay - gy), fminf(gz - ax, gw - ay));
    return d > 1e-9f;
}

// anchor index -> grid-point coords, bitwise == anc[] ((i+0.5)*s, s pow2)
__device__ __forceinline__ void anchor_xy(int a, float& ax, float& ay) {
    if (a < 6400)      { int iy = a / 80;        int ix = a - iy * 80;           ax = (ix + 0.5f) * 8.f;  ay = (iy + 0.5f) * 8.f; }
    else if (a < 8000) { int r = a - 6400; int iy = r / 40; int ix = r - iy * 40; ax = (ix + 0.5f) * 16.f; ay = (iy + 0.5f) * 16.f; }
    else               { int r = a - 8000; int iy = r / 20; int ix = r - iy * 20; ax = (ix + 0.5f) * 32.f; ay = (iy + 0.5f) * 32.f; }
}

// K1: one WAVE per (b,m). Enumerate candidate anchors from the box's grid
// rectangles (3 levels), compact positives to LDS, 13 shuffle-argmax rounds
// (exact lax.top_k semantics: lowest-index ties + npos<13 zero-fill).
// Publishes the row's gt-side atanf into at_g_tbl.
__global__ __launch_bounds__(64) void k_topk(
    const float* __restrict__ pd_scores, const float* __restrict__ pd_bboxes,
    const int* __restrict__ gt_labels, const float* __restrict__ gt_bboxes,
    const float* __restrict__ mask_gt,
    int* __restrict__ fg_cnt, int* __restrict__ fg_m,
    float* __restrict__ at_g_tbl)
{
    __shared__ float cv[NCAND];
    __shared__ int   ca[NCAND];
    __shared__ int   s_cnt;
    __shared__ unsigned s_pm;           // "align>0" mask for anchors 0..31

    int bm = blockIdx.x;
    if (mask_gt[bm] <= 0.f) return;
    int b = bm >> 7;                    // MG = 128
    int m = bm & (MG - 1);
    int tid = threadIdx.x;

    if (tid == 0) { s_cnt = 0; s_pm = 0u; }
    __syncthreads();

    const float4 g = *reinterpret_cast<const float4*>(gt_bboxes + bm * 4);
    const int lbl = gt_labels[bm];
    const float* pbb = pd_bboxes + (size_t)b * NA * 4;
    const float* psc = pd_scores + (size_t)b * NA * NC;
    const float at_g = atanf((g.z - g.x) / (g.w - g.y + 1e-7f));  // block-invariant
    if (tid == 0) at_g_tbl[bm] = at_g;

    auto do_level = [&](float s, int n, int base) {
        // conservative rectangle (+-1 cell); exact inside_gt per candidate
        // keeps the positive set bitwise-identical.
        int xlo = max(0, (int)floorf(g.x / s - 0.5f) - 1);
        int xhi = min(n - 1, (int)ceilf(g.z / s - 0.5f) + 1);
        int ylo = max(0, (int)floorf(g.y / s - 0.5f) - 1);
        int yhi = min(n - 1, (int)ceilf(g.w / s - 0.5f) + 1);
        int w = xhi - xlo + 1, h = yhi - ylo + 1;
        if (w <= 0 || h <= 0) return;
        int cnt = w * h;
        for (int idx = tid; idx < cnt; idx += 64) {
            int iy = ylo + idx / w;
            int ix = xlo + idx - (idx / w) * w;
            float ax = (ix + 0.5f) * s;
            float ay = (iy + 0.5f) * s;
            if (!inside_gt(ax, ay, g.x, g.y, g.z, g.w)) continue;
            int a = base + iy * n + ix;
            float4 p = *reinterpret_cast<const float4*>(pbb + (size_t)a * 4);
            float dat = atanf((p.z - p.x) / (p.w - p.y + 1e-7f)) - at_g;
            float ov = fmaxf(ciou_pre(g.x, g.y, g.z, g.w, p.x, p.y, p.z, p.w, dat), 0.f);
            float sc = psc[(size_t)a * NC + lbl];
            float ov2 = ov * ov;
            float al = sc * ov2 * ov2 * ov2;     // score^1 * ov^6
            if (al > 0.f) {
                int slot = atomicAdd(&s_cnt, 1);
                if (slot < NCAND) { cv[slot] = al; ca[slot] = a; }
                if (a < 32) atomicOr(&s_pm, 1u << a);
            }
        }
    };
    do_level(8.f, 80, 0);
    do_level(16.f, 40, 6400);
    do_level(32.f, 20, 8000);
    __syncthreads();

    int npos = min(s_cnt, NCAND);
    int rounds = min(npos, TK);
    int* fgc = fg_cnt + b * NA;
    int* fgm = fg_m + b * NA;

    for (int k = 0; k < rounds; ++k) {
        float bv = -1.f; int bk = 0x7fffffff;
        for (int p = tid; p < npos; p += 64) {
            float v = cv[p];
            int key = (ca[p] << 11) | p;         // anchor high bits: ties -> lowest anchor
            if (v > bv || (v == bv && key < bk)) { bv = v; bk = key; }
        }
        #pragma unroll
        for (int off = 32; off > 0; off >>= 1) {
            float v2 = __shfl_down(bv, off);
            int   k2 = __shfl_down(bk, off);
            if (v2 > bv || (v2 == bv && k2 < bk)) { bv = v2; bk = k2; }
        }
        if (tid == 0) {
            int slot = bk & 2047;
            int a = bk >> 11;
            cv[slot] = -1.f;                     // remove winner
            atomicAdd(&fgc[a], 1);
            fgm[a] = m;                          // unique writer when final cnt==1
        }
        __syncthreads();
    }

    // npos < TK: top_k pads with globally lowest-index zero-valued anchors
    // (indices provably < 26 < 32); mask_in_gts then filters them.
    if (tid == 0) {
        int need = TK - rounds;
        unsigned pm = s_pm;
        for (int idx = 0; idx < 32 && need > 0; ++idx) {
            if (!((pm >> idx) & 1u)) {
                float ax = (idx + 0.5f) * 8.f, ay = 4.f;
                if (inside_gt(ax, ay, g.x, g.y, g.z, g.w)) {
                    atomicAdd(&fgc[idx], 1);
                    fgm[idx] = m;
                }
                --need;
            }
        }
    }
}

// K2: per anchor, fused. cnt==1 direct; cnt>1 resolved WAVE-COOPERATIVELY:
// ballot the multi lanes, loop the set bits (wave-uniform, ~11 iters avg),
// all 64 lanes jointly do the 128-way masked-overlap argmax (2 CIoU/lane +
// shuffle reduce, first-max tie-break == k_fix == jnp.argmax).
__global__ __launch_bounds__(256) void k_assign(
    const float* __restrict__ pd_scores, const float* __restrict__ pd_bboxes,
    const int* __restrict__ gt_labels, const float* __restrict__ gt_bboxes,
    const float* __restrict__ mask_gt, const float* __restrict__ at_g_tbl,
    const int* __restrict__ fg_cnt, const int* __restrict__ fg_m,
    float* __restrict__ out, float* __restrict__ am_ws,
    int* __restrict__ gi_ws, int* __restrict__ lbl_ws,
    unsigned* __restrict__ pos_am, unsigned* __restrict__ pos_ov)
{
    int tid = threadIdx.x;
    int i = blockIdx.x * 256 + tid;              // grid exact: 134400 = 525*256
    int cnt = fg_cnt[i];
    int b = i / NA, a = i - b * NA;
    int gbase = b * MG;
    int lane = tid & 63;
    bool multi = cnt > 1;

    int t = 0;
    float bovm = -1.f;                           // multi-path winning overlap

    // --- wave-cooperative multi resolution (wave-uniform loop) ---
    unsigned long long mk = __ballot(multi);
    while (mk) {
        int l = __ffsll((long long)mk) - 1; mk &= mk - 1ull;
        int ii = __shfl(i, l);
        int bb = ii / NA, aa = ii - bb * NA;
        int gb = bb * MG;
        float ax, ay; anchor_xy(aa, ax, ay);
        float4 p = *reinterpret_cast<const float4*>(pd_bboxes + (size_t)ii * 4);
        float at_p = atanf((p.z - p.x) / (p.w - p.y + 1e-7f));

        auto ovm = [&](int mm) -> float {
            int gi = gb + mm;
            float ov = 0.f;
            if (mask_gt[gi] > 0.f) {
                float4 gg = *reinterpret_cast<const float4*>(gt_bboxes + gi * 4);
                if (inside_gt(ax, ay, gg.x, gg.y, gg.z, gg.w)) {
                    float dat = at_p - at_g_tbl[gi];
                    ov = fmaxf(ciou_pre(gg.x, gg.y, gg.z, gg.w, p.x, p.y, p.z, p.w, dat), 0.f);
                }
            }
            return ov;
        };
        float ov0 = ovm(lane);
        float ov1 = ovm(lane + 64);
        float bov; int bmx;
        if (ov1 > ov0) { bov = ov1; bmx = lane + 64; }
        else           { bov = ov0; bmx = lane; }
        #pragma unroll
        for (int off = 32; off > 0; off >>= 1) {
            float v2 = __shfl_down(bov, off);
            int   m2 = __shfl_down(bmx, off);
            if (v2 > bov || (v2 == bov && m2 < bmx)) { bov = v2; bmx = m2; }
        }
        bov = __shfl(bov, 0);
        bmx = __shfl(bmx, 0);
        if (lane == l) { t = bmx; bovm = bov; }
    }

    if (!multi && cnt == 1) t = fg_m[i];

    int gi = gbase + t;
    float4 g = *reinterpret_cast<const float4*>(gt_bboxes + gi * 4);
    int lraw = gt_labels[gi];
    int lbl = max(lraw, 0);

    float am = 0.f, ovv = 0.f;
    if (multi) {
        if (bovm > 0.f) {                        // implies mask && inside at t
            float sc = pd_scores[(size_t)i * NC + lraw];
            float o2 = bovm * bovm;
            am = sc * o2 * o2 * o2;
            ovv = bovm;
        }
    } else if (cnt == 1) {
        if (mask_gt[gi] > 0.f) {
            float ax, ay; anchor_xy(a, ax, ay);
            if (inside_gt(ax, ay, g.x, g.y, g.z, g.w)) {
                float4 p = *reinterpret_cast<const float4*>(pd_bboxes + (size_t)i * 4);
                float dat = atanf((p.z - p.x) / (p.w - p.y + 1e-7f)) - at_g_tbl[gi];
                float ov = fmaxf(ciou_pre(g.x, g.y, g.z, g.w, p.x, p.y, p.z, p.w, dat), 0.f);
                float sc = pd_scores[(size_t)i * NC + lraw];
                float ov2 = ov * ov;
                am = sc * ov2 * ov2 * ov2;
                ovv = ov;
            }
        }
    }

    if (cnt > 0) {
        atomicMax(&pos_am[gi], __float_as_uint(am));
        atomicMax(&pos_ov[gi], __float_as_uint(ovv));
        am_ws[i] = am; gi_ws[i] = gi; lbl_ws[i] = lbl;
    } else {
        gi_ws[i] = -1;                           // background
    }

    out[OFF_LBL + i] = (float)lbl;
    reinterpret_cast<float4*>(out + OFF_BB)[i] = g;
    out[OFF_FG + i] = cnt ? 1.f : 0.f;
    out[OFF_TG + i] = (float)t;
}

// K3: dense coalesced write of target_scores (no memset, no scatter atomics).
__global__ __launch_bounds__(256) void k_scores(
    const float* __restrict__ am_ws, const int* __restrict__ gi_ws,
    const int* __restrict__ lbl_ws,
    const unsigned* __restrict__ pos_am, const unsigned* __restrict__ pos_ov,
    float* __restrict__ out_scores)
{
    constexpr int NQ = NC / 4;                   // 20 float4s per anchor
    int idx = blockIdx.x * 256 + threadIdx.x;    // grid exact: 134400*20 = 10500*256
    int i = idx / NQ;
    int q = idx - i * NQ;
    float4 v = {0.f, 0.f, 0.f, 0.f};
    int gi = gi_ws[i];
    if (gi >= 0) {
        int lbl = lbl_ws[i];
        if ((lbl >> 2) == q) {
            float norm = am_ws[i] * __uint_as_float(pos_ov[gi]) /
                         (__uint_as_float(pos_am[gi]) + 1e-9f);
            reinterpret_cast<float*>(&v)[lbl & 3] = norm;
        }
    }
    reinterpret_cast<float4*>(out_scores)[idx] = v;
}

extern "C" void kernel_launch(void* const* d_in, const int* in_sizes, int n_in,
                              void* d_out, int out_size, void* d_ws, size_t ws_size,
                              hipStream_t stream) {
    const float* pd_scores = (const float*)d_in[0];
    const float* pd_bboxes = (const float*)d_in[1];
    const int*   gt_labels = (const int*)d_in[3];
    const float* gt_bboxes = (const float*)d_in[4];
    const float* mask_gt   = (const float*)d_in[5];
    float* out = (float*)d_out;

    // Workspace carve. Zeroed region first (fg_cnt + pos_am + pos_ov).
    unsigned char* w = (unsigned char*)d_ws;
    size_t off = 0;
    int*      fg_cnt   = (int*)(w + off);      off += (size_t)BS * NA * 4;
    unsigned* pos_am   = (unsigned*)(w + off); off += (size_t)BS * MG * 4;
    unsigned* pos_ov   = (unsigned*)(w + off); off += (size_t)BS * MG * 4;
    size_t zero_bytes = off;
    int*      fg_m     = (int*)(w + off);      off += (size_t)BS * NA * 4;
    float*    am_ws    = (float*)(w + off);    off += (size_t)BS * NA * 4;
    int*      gi_ws    = (int*)(w + off);      off += (size_t)BS * NA * 4;
    int*      lbl_ws   = (int*)(w + off);      off += (size_t)BS * NA * 4;
    float*    at_g_tbl = (float*)(w + off);    off += (size_t)BS * MG * 4;

    hipMemsetAsync(w, 0, zero_bytes, stream);

    k_topk<<<BS * MG, 64, 0, stream>>>(pd_scores, pd_bboxes, gt_labels,
                                       gt_bboxes, mask_gt, fg_cnt, fg_m,
                                       at_g_tbl);

    int nA = BS * NA;                            // 134400 = 525 * 256
    k_assign<<<nA / 256, 256, 0, stream>>>(
        pd_scores, pd_bboxes, gt_labels, gt_bboxes, mask_gt, at_g_tbl,
        fg_cnt, fg_m, out, am_ws, gi_ws, lbl_ws, pos_am, pos_ov);

    k_scores<<<nA * (NC / 4) / 256, 256, 0, stream>>>(
        am_ws, gi_ws, lbl_ws, pos_am, pos_ov, out + OFF_SC);
}